// Round 14
// baseline (579.765 us; speedup 1.0000x reference)
//
#include <hip/hip_runtime.h>
#include <math.h>

#define D_MODEL 512
#define N_HEADS 8
#define D_KH    64
#define D_FF    2048
#define N_LAYERS 4
#define BSZ     4
#define SEQ     1024

typedef __attribute__((ext_vector_type(8))) __bf16 bf16x8;
typedef __attribute__((ext_vector_type(8))) short  s16x8;
typedef __attribute__((ext_vector_type(4))) float  f32x4;

union BF8 { s16x8 s; bf16x8 b; };

static __device__ inline unsigned short f2b(float f) {
    unsigned u = __float_as_uint(f);
    unsigned r = (u + 0x7fffu + ((u >> 16) & 1u)) >> 16;   // RNE
    return (unsigned short)r;
}

// async global->LDS 16B: lds dest = wave-uniform base + lane*16; global src per-lane.
static __device__ __forceinline__ void async16(const unsigned short* g, unsigned short* l) {
    __builtin_amdgcn_global_load_lds((const __attribute__((address_space(1))) unsigned int*)g,
                                     (__attribute__((address_space(3))) unsigned int*)l, 16, 0, 0);
}

// ---------------- embedding + pos-enc (fp32 + bf16 shadow) AND enc_out convert ------
__global__ void embed_cvt_kernel(const int* __restrict__ dec, const float* __restrict__ emb,
                                 float* __restrict__ x, unsigned short* __restrict__ xb,
                                 const float* __restrict__ enc_out, unsigned short* __restrict__ encb) {
    const int NE = BSZ * SEQ * D_MODEL;                 // 2M
    int idx = blockIdx.x * blockDim.x + threadIdx.x;
    if (idx < NE) {
        int d  = idx % D_MODEL;
        int bs = idx / D_MODEL;
        int s  = bs % SEQ;
        int tok = dec[bs];
        float pos = (float)(s + 5);
        float e = (float)(d & ~1) * (1.0f / (float)D_MODEL);
        float ang = pos * __expf(-9.210340372f * e);    // 10000^-e
        float pe = (d & 1) ? __cosf(ang) : __sinf(ang);
        float v = emb[(size_t)tok * D_MODEL + d] + pe;
        x[idx] = v;
        xb[idx] = f2b(v);
    } else {
        int i = idx - NE;                               // float4 index over NE/4
        if (i < NE / 4) {
            float4 f = ((const float4*)enc_out)[i];
            ushort4 h;
            h.x = f2b(f.x); h.y = f2b(f.y); h.z = f2b(f.z); h.w = f2b(f.w);
            ((ushort4*)encb)[i] = h;
        }
    }
}

// ---------------- ALL weight transposes in one launch: src[K][N] f32 -> dst[N][K] bf16
__global__ void wt_all_kernel(const float* __restrict__ selfW, const float* __restrict__ encW,
                              const float* __restrict__ W1, const float* __restrict__ W2,
                              unsigned short* __restrict__ wtS, unsigned short* __restrict__ wtE,
                              unsigned short* __restrict__ wtF1, unsigned short* __restrict__ wtF2) {
    __shared__ unsigned short Tb[64][72];
    int tile = blockIdx.x;                 // 4096 tiles, 1024 per weight group
    int which = tile >> 10, rem = tile & 1023;
    const float* src; unsigned short* dst; int K, N, z, kt, ntile;
    if (which <= 1) {
        src = which ? encW : selfW; dst = which ? wtE : wtS;
        K = 512; N = 512;
        z = rem >> 6; int r2 = rem & 63; kt = r2 & 7; ntile = r2 >> 3;
    } else if (which == 2) {
        src = W1; dst = wtF1; K = 512; N = 2048;
        z = rem >> 8; int r2 = rem & 255; kt = r2 & 7; ntile = r2 >> 3;
    } else {
        src = W2; dst = wtF2; K = 2048; N = 512;
        z = rem >> 8; int r2 = rem & 255; kt = r2 >> 3; ntile = r2 & 7;
    }
    int k0 = kt * 64, n0 = ntile * 64;
    size_t zoff = (size_t)z * K * N;
    src += zoff; dst += zoff;
    int t = threadIdx.x;
    int kr = t & 63, sg = t >> 6;
    const float* sp = src + (size_t)(k0 + kr) * N + n0 + sg * 16;
    #pragma unroll
    for (int j = 0; j < 4; j++) {
        float4 f = *(const float4*)(sp + 4 * j);
        Tb[sg * 16 + 4 * j + 0][kr] = f2b(f.x);
        Tb[sg * 16 + 4 * j + 1][kr] = f2b(f.y);
        Tb[sg * 16 + 4 * j + 2][kr] = f2b(f.z);
        Tb[sg * 16 + 4 * j + 3][kr] = f2b(f.w);
    }
    __syncthreads();
    unsigned short* dp = dst + (size_t)(n0 + kr) * K + k0 + sg * 16;
    *(s16x8*)(dp)     = *(const s16x8*)&Tb[kr][sg * 16];
    *(s16x8*)(dp + 8) = *(const s16x8*)&Tb[kr][sg * 16 + 8];
}

// ---------------- mask prep: enc pad-key compaction + dec pad-tile flags ------------
__global__ void prep_kernel(const int* __restrict__ dec, const int* __restrict__ enc,
                            int* __restrict__ cntEnc, int* __restrict__ listEnc,
                            int* __restrict__ anyPadDec) {
    int b = blockIdx.x;
    int lane = threadIdx.x;
    int base = 0;
    for (int c0 = 0; c0 < SEQ; c0 += 64) {
        bool z = (enc[b * SEQ + c0 + lane] == 0);
        unsigned long long mask = __ballot(z);
        int pre = __popcll(mask & ((1ull << lane) - 1ull));
        if (z) listEnc[b * SEQ + base + pre] = c0 + lane;
        base += __popcll(mask);
    }
    if (lane == 0) cntEnc[b] = base;
    for (int c0 = 0; c0 < SEQ; c0 += 64) {
        bool z = (dec[b * SEQ + c0 + lane] == 0);
        unsigned long long mask = __ballot(z);
        if (lane == 0) anyPadDec[b * (SEQ / 64) + (c0 >> 6)] = (mask != 0ull) ? 1 : 0;
    }
}

// ---------------- bf16 MFMA GEMM 64x64 core (shared by all 64-tile variants) --------
// acc over K tiles of 64; A,B both [64][64] swizzled in LDS; 2x2 waves of 32x32.
#define GEMM64_BODY(ABASE, BBASE, KDIM)                                              \
    int t = threadIdx.x, w = t >> 6, lane = t & 63;                                  \
    int wm = w >> 1, wn = w & 1;                                                     \
    int g = lane >> 4, c = lane & 15;                                                \
    int l3 = lane >> 3, l7 = lane & 7;                                               \
    int srcoff = 8 * (l7 ^ l3);                                                      \
    f32x4 acc[2][2];                                                                 \
    _Pragma("unroll")                                                                \
    for (int mi = 0; mi < 2; mi++)                                                   \
        _Pragma("unroll")                                                            \
        for (int nj = 0; nj < 2; nj++) acc[mi][nj] = (f32x4){0.f, 0.f, 0.f, 0.f};    \
    int nt = (KDIM) >> 6;                                                            \
    STG(0, 0);                                                                       \
    __syncthreads();                                                                 \
    for (int kt = 0; kt < nt; kt++) {                                                \
        int cur = kt & 1;                                                            \
        if (kt + 1 < nt) STG(cur ^ 1, kt + 1);                                       \
        const unsigned short* Lb = &lds[cur][0];                                     \
        BF8 a[2][2], b[2][2];                                                        \
        _Pragma("unroll")                                                            \
        for (int kk = 0; kk < 2; kk++) {                                             \
            int xo = (kk * 32 + g * 8) ^ ((c & 7) * 8);                              \
            _Pragma("unroll")                                                        \
            for (int mi = 0; mi < 2; mi++)                                           \
                a[kk][mi].s = *(const s16x8*)&Lb[(wm * 32 + mi * 16 + c) * 64 + xo]; \
            _Pragma("unroll")                                                        \
            for (int nj = 0; nj < 2; nj++)                                           \
                b[kk][nj].s = *(const s16x8*)&Lb[4096 + (wn * 32 + nj * 16 + c) * 64 + xo]; \
        }                                                                            \
        _Pragma("unroll")                                                            \
        for (int kk = 0; kk < 2; kk++)                                               \
            _Pragma("unroll")                                                        \
            for (int mi = 0; mi < 2; mi++)                                           \
                _Pragma("unroll")                                                    \
                for (int nj = 0; nj < 2; nj++)                                       \
                    acc[mi][nj] = __builtin_amdgcn_mfma_f32_16x16x32_bf16(a[kk][mi].b, b[kk][nj].b, acc[mi][nj], 0, 0, 0); \
        __syncthreads();                                                             \
    }

#define STG_IMPL(BUF, KT, ABASE, BBASE, KDIM)                                        \
    do {                                                                             \
        unsigned short* Lb_ = &lds[BUF][0];                                          \
        int k0_ = (KT) * 64;                                                         \
        _Pragma("unroll")                                                            \
        for (int i_ = 0; i_ < 2; i_++) {                                             \
            int q_ = w * 2 + i_;                                                     \
            async16(ABASE + (size_t)(q_ * 8 + l3) * (KDIM) + k0_ + srcoff, Lb_ + q_ * 512); \
            async16(BBASE + (size_t)(q_ * 8 + l3) * (KDIM) + k0_ + srcoff, Lb_ + 4096 + q_ * 512); \
        }                                                                            \
    } while (0)

// ---------------- bf16 MFMA GEMM 64x64 (generic: out-proj, Q-cross, FFN2) -----------
template<int OUTBF16, int RELU>
__launch_bounds__(256, 4)
__global__ void gemm64_kernel(const unsigned short* __restrict__ A,
                              const unsigned short* __restrict__ Wt, const float* __restrict__ bias,
                              void* __restrict__ C_, int M, int N, int K) {
    __shared__ unsigned short lds[2][8192];
    int m0 = blockIdx.x * 64, n0 = blockIdx.y * 64;
    const unsigned short* Abase = A  + (size_t)m0 * K;
    const unsigned short* Bbase = Wt + (size_t)n0 * K;
#define STG(BUF, KT) STG_IMPL(BUF, KT, Abase, Bbase, K)
    GEMM64_BODY(Abase, Bbase, K)
#undef STG
    #pragma unroll
    for (int mi = 0; mi < 2; mi++) {
        #pragma unroll
        for (int nj = 0; nj < 2; nj++) {
            #pragma unroll
            for (int r = 0; r < 4; r++) {
                int row = m0 + wm * 32 + mi * 16 + g * 4 + r;
                int col = n0 + wn * 32 + nj * 16 + c;
                float v = acc[mi][nj][r] + bias[col];
                if (RELU) v = fmaxf(v, 0.0f);
                if (OUTBF16) ((unsigned short*)C_)[(size_t)row * N + col] = f2b(v);
                else         ((float*)C_)[(size_t)row * N + col] = v;
            }
        }
    }
}

// ---------------- merged self-QKV, 64x64 tiles, z selects {Q,K,V} -------------------
// grid (M/64, 8, 3) = 1536 blocks = 16 resident waves/CU.
__launch_bounds__(256, 4)
__global__ void gemm64_qkv_kernel(const unsigned short* __restrict__ A,
                                  const unsigned short* __restrict__ sWt, const float* __restrict__ sb,
                                  unsigned short* __restrict__ Qo, unsigned short* __restrict__ Ko,
                                  unsigned short* __restrict__ Vo) {
    __shared__ unsigned short lds[2][8192];
    const int K = D_MODEL, N = D_MODEL;
    int j = blockIdx.z;
    const unsigned short* Wt = sWt + (size_t)j * (D_MODEL * D_MODEL);
    const float* bias = sb + j * D_MODEL;
    unsigned short* C_ = (j == 0) ? Qo : (j == 1) ? Ko : Vo;
    int m0 = blockIdx.x * 64, n0 = blockIdx.y * 64;
    const unsigned short* Abase = A  + (size_t)m0 * K;
    const unsigned short* Bbase = Wt + (size_t)n0 * K;
#define STG(BUF, KT) STG_IMPL(BUF, KT, Abase, Bbase, K)
    GEMM64_BODY(Abase, Bbase, K)
#undef STG
    #pragma unroll
    for (int mi = 0; mi < 2; mi++) {
        #pragma unroll
        for (int nj = 0; nj < 2; nj++) {
            #pragma unroll
            for (int r = 0; r < 4; r++) {
                int row = m0 + wm * 32 + mi * 16 + g * 4 + r;
                int col = n0 + wn * 32 + nj * 16 + c;
                C_[(size_t)row * N + col] = f2b(acc[mi][nj][r] + bias[col]);
            }
        }
    }
}

// ---------------- batched cross-attn K/V projections (layer-invariant A = encb) -----
// grid (M/64, 8, 8); z = L*2 + (0=K,1=V). Computed ONCE per call in the prologue.
__launch_bounds__(256, 4)
__global__ void gemm_kv_kernel(const unsigned short* __restrict__ A,
                               const unsigned short* __restrict__ wtE, const float* __restrict__ enc_b,
                               unsigned short* __restrict__ outKV) {
    __shared__ unsigned short lds[2][8192];
    const int K = D_MODEL, N = D_MODEL;
    int j = blockIdx.z, L = j >> 1, kv = j & 1;
    const unsigned short* Wt = wtE + ((size_t)L * 4 + 1 + kv) * (D_MODEL * D_MODEL);
    const float* bias = enc_b + (L * 4 + 1 + kv) * D_MODEL;
    unsigned short* C_ = outKV + (size_t)j * (BSZ * SEQ) * D_MODEL;
    int m0 = blockIdx.x * 64, n0 = blockIdx.y * 64;
    const unsigned short* Abase = A  + (size_t)m0 * K;
    const unsigned short* Bbase = Wt + (size_t)n0 * K;
#define STG(BUF, KT) STG_IMPL(BUF, KT, Abase, Bbase, K)
    GEMM64_BODY(Abase, Bbase, K)
#undef STG
    #pragma unroll
    for (int mi = 0; mi < 2; mi++) {
        #pragma unroll
        for (int nj = 0; nj < 2; nj++) {
            #pragma unroll
            for (int r = 0; r < 4; r++) {
                int row = m0 + wm * 32 + mi * 16 + g * 4 + r;
                int col = n0 + wn * 32 + nj * 16 + c;
                C_[(size_t)row * N + col] = f2b(acc[mi][nj][r] + bias[col]);
            }
        }
    }
}

// ---------------- bf16 MFMA GEMM 128x128, wave tile 64x64 (FFN1: 512 blocks=2/CU) ---
template<int OUTBF16, int RELU>
__launch_bounds__(256, 2)
__global__ void gemm128_kernel(const unsigned short* __restrict__ A,
                               const unsigned short* __restrict__ Wt, const float* __restrict__ bias,
                               void* __restrict__ C_, int M, int N, int K) {
    __shared__ unsigned short lds[2][16384];   // [A 128x64 | B 128x64] x 2 buf = 64KB
    int m0 = blockIdx.x * 128, n0 = blockIdx.y * 128;

    int t = threadIdx.x, w = t >> 6, lane = t & 63;
    int wm = w >> 1, wn = w & 1;               // 2x2 wave grid, wave tile 64x64
    int g = lane >> 4, c = lane & 15;
    int l3 = lane >> 3, l7 = lane & 7;
    int srcoff = 8 * (l7 ^ l3);

    const unsigned short* Abase = A  + (size_t)m0 * K;
    const unsigned short* Bbase = Wt + (size_t)n0 * K;

    f32x4 acc[4][4];
    #pragma unroll
    for (int mi = 0; mi < 4; mi++)
        #pragma unroll
        for (int nj = 0; nj < 4; nj++) acc[mi][nj] = (f32x4){0.f, 0.f, 0.f, 0.f};

#define STAGE128(BUF, KT) do {                                                      \
        unsigned short* Lb_ = &lds[BUF][0];                                         \
        int k0_ = (KT) * 64;                                                        \
        _Pragma("unroll")                                                           \
        for (int i_ = 0; i_ < 4; i_++) {                                            \
            int q_ = w * 4 + i_;                                                    \
            async16(Abase + (size_t)(q_ * 8 + l3) * K + k0_ + srcoff, Lb_ + q_ * 512); \
            async16(Bbase + (size_t)(q_ * 8 + l3) * K + k0_ + srcoff, Lb_ + 8192 + q_ * 512); \
        }                                                                           \
    } while (0)

    int nt = K >> 6;
    STAGE128(0, 0);
    __syncthreads();
    for (int kt = 0; kt < nt; kt++) {
        int cur = kt & 1;
        if (kt + 1 < nt) STAGE128(cur ^ 1, kt + 1);
        const unsigned short* Lb = &lds[cur][0];
        BF8 a[2][4], b[2][4];
        #pragma unroll
        for (int kk = 0; kk < 2; kk++) {
            int xo = (kk * 32 + g * 8) ^ ((c & 7) * 8);
            #pragma unroll
            for (int mi = 0; mi < 4; mi++)
                a[kk][mi].s = *(const s16x8*)&Lb[(wm * 64 + mi * 16 + c) * 64 + xo];
            #pragma unroll
            for (int nj = 0; nj < 4; nj++)
                b[kk][nj].s = *(const s16x8*)&Lb[8192 + (wn * 64 + nj * 16 + c) * 64 + xo];
        }
        #pragma unroll
        for (int kk = 0; kk < 2; kk++)
            #pragma unroll
            for (int mi = 0; mi < 4; mi++)
                #pragma unroll
                for (int nj = 0; nj < 4; nj++)
                    acc[mi][nj] = __builtin_amdgcn_mfma_f32_16x16x32_bf16(a[kk][mi].b, b[kk][nj].b, acc[mi][nj], 0, 0, 0);
        __syncthreads();
    }
#undef STAGE128

    #pragma unroll
    for (int mi = 0; mi < 4; mi++) {
        #pragma unroll
        for (int nj = 0; nj < 4; nj++) {
            #pragma unroll
            for (int r = 0; r < 4; r++) {
                int row = m0 + wm * 64 + mi * 16 + g * 4 + r;
                int col = n0 + wn * 64 + nj * 16 + c;
                float v = acc[mi][nj][r] + bias[col];
                if (RELU) v = fmaxf(v, 0.0f);
                if (OUTBF16) ((unsigned short*)C_)[(size_t)row * N + col] = f2b(v);
                else         ((float*)C_)[(size_t)row * N + col] = v;
            }
        }
    }
}

// ---------------- MFMA bf16 flash attention: 4 waves, K/V LDS double-buffered -------
#define RS 72
template<int MODE>
__global__ void attn_kernel(const unsigned short* __restrict__ Q, const unsigned short* __restrict__ K,
                            const unsigned short* __restrict__ V, const int* __restrict__ ids,
                            const int* __restrict__ list, const int* __restrict__ cnt,
                            const int* __restrict__ anyPad,
                            unsigned short* __restrict__ O_, int Sq, int Sk) {
    __shared__ unsigned short Kl[2][64][RS];
    __shared__ unsigned short Vt[2][64][RS];
    __shared__ unsigned short Ps[4][16][RS];
    __shared__ short act[16];
    __shared__ int nActS;

    int blk = blockIdx.x;
    int qt, bh;
    if (MODE) {
        int hi = blk >> 8, pair = blk & 255;
        bh = pair >> 3;
        int qtp = pair & 7;
        qt = hi ? (15 - qtp) : qtp;             // pair work: (qtp+1)+(16-qtp)=17 tiles
    } else {
        qt = blk & 15;
        bh = blk >> 4;
    }
    int h = bh % N_HEADS;
    int b = bh / N_HEADS;
    int qbase = qt * 64;
    int t = threadIdx.x;
    int w = t >> 6, lane = t & 63;
    int g = lane >> 4, c = lane & 15;

    BF8 qf[2];
    {
        int qrow = qbase + w * 16 + c;
        const unsigned short* qp = Q + ((size_t)(b * Sq + qrow)) * D_MODEL + h * D_KH;
        qf[0].s = *(const s16x8*)(qp + 8 * g);
        qf[1].s = *(const s16x8*)(qp + 8 * g + 32);
    }

    int nk = 0;
    bool gathered = false;
    if (!MODE) {
        nk = cnt[b];
        gathered = (nk > 0);
    }

    if (t == 0) {
        int n = 0;
        if (MODE) {
            for (int kt2 = 0; kt2 < (Sk >> 6); kt2++)
                if (kt2 <= qt || anyPad[b * (Sk >> 6) + kt2]) act[n++] = (short)kt2;
        } else {
            int tt = gathered ? ((nk + 63) >> 6) : (Sk >> 6);
            for (int kt2 = 0; kt2 < tt; kt2++) act[n++] = (short)kt2;
        }
        nActS = n;
    }
    __syncthreads();
    int nAct = nActS;

    float m[4], l[4];
    f32x4 Oacc[4];
    #pragma unroll
    for (int r = 0; r < 4; r++) { m[r] = -INFINITY; l[r] = 0.0f; }
    #pragma unroll
    for (int ds = 0; ds < 4; ds++) Oacc[ds] = (f32x4){0.f, 0.f, 0.f, 0.f};

    s16x8 kreg0, kreg1, vreg0, vreg1;
    int kr0 = t >> 3,        ks0 = t & 7;
    int kr1 = (t + 256) >> 3, ks1 = (t + 256) & 7;

#define LOADT(KT) do {                                                                \
        int k0_ = (KT) * 64;                                                          \
        int krow0 = k0_ + kr0, krow1 = k0_ + kr1;                                     \
        if (gathered) {                                                               \
            krow0 = list[b * Sk + (krow0 < nk ? krow0 : nk - 1)];                     \
            krow1 = list[b * Sk + (krow1 < nk ? krow1 : nk - 1)];                     \
        }                                                                             \
        kreg0 = *(const s16x8*)(K + ((size_t)(b * Sk + krow0)) * D_MODEL + h * D_KH + ks0 * 8); \
        kreg1 = *(const s16x8*)(K + ((size_t)(b * Sk + krow1)) * D_MODEL + h * D_KH + ks1 * 8); \
        int li = k0_ + lane, vrow = li;                                               \
        if (gathered) vrow = list[b * Sk + (li < nk ? li : nk - 1)];                  \
        const unsigned short* vp = V + ((size_t)(b * Sk + vrow)) * D_MODEL + h * D_KH + w * 16; \
        vreg0 = *(const s16x8*)(vp);                                                  \
        vreg1 = *(const s16x8*)(vp + 8);                                              \
    } while (0)

#define WRITET(BUF) do {                                                              \
        *(s16x8*)&Kl[BUF][kr0][ks0 * 8] = kreg0;                                      \
        *(s16x8*)&Kl[BUF][kr1][ks1 * 8] = kreg1;                                      \
        _Pragma("unroll")                                                             \
        for (int j = 0; j < 8; j++) Vt[BUF][w * 16 + j][lane] = ((unsigned short*)&vreg0)[j]; \
        _Pragma("unroll")                                                             \
        for (int j = 0; j < 8; j++) Vt[BUF][w * 16 + 8 + j][lane] = ((unsigned short*)&vreg1)[j]; \
    } while (0)

    LOADT(act[0]);
    WRITET(0);
    __syncthreads();
    for (int i = 0; i < nAct; i++) {
        int cur = i & 1;
        int k0 = (int)act[i] * 64;
        if (i + 1 < nAct) LOADT(act[i + 1]);    // latency hides under compute below

        f32x4 S[4];
        #pragma unroll
        for (int sub = 0; sub < 4; sub++) {
            BF8 b0, b1;
            b0.s = *(const s16x8*)&Kl[cur][sub * 16 + c][8 * g];
            b1.s = *(const s16x8*)&Kl[cur][sub * 16 + c][8 * g + 32];
            f32x4 s = (f32x4){0.f, 0.f, 0.f, 0.f};
            s = __builtin_amdgcn_mfma_f32_16x16x32_bf16(qf[0].b, b0.b, s, 0, 0, 0);
            s = __builtin_amdgcn_mfma_f32_16x16x32_bf16(qf[1].b, b1.b, s, 0, 0, 0);
            S[sub] = s;
        }

        #pragma unroll
        for (int sub = 0; sub < 4; sub++) {
            int k = k0 + sub * 16 + c;
            bool pad;
            if (MODE) pad = (ids[b * Sk + k] == 0);
            else      pad = gathered ? (k < nk) : false;
            #pragma unroll
            for (int r = 0; r < 4; r++) {
                bool att;
                if (MODE) {
                    int qrow = qbase + w * 16 + g * 4 + r;
                    att = pad || (k <= qrow);
                } else att = pad;
                S[sub][r] = att ? S[sub][r] * 0.125f : -1e9f;
            }
        }

        #pragma unroll
        for (int r = 0; r < 4; r++) {
            float mx = fmaxf(fmaxf(S[0][r], S[1][r]), fmaxf(S[2][r], S[3][r]));
            #pragma unroll
            for (int o = 8; o > 0; o >>= 1) mx = fmaxf(mx, __shfl_xor(mx, o));
            float mn = fmaxf(m[r], mx);
            float sc = __expf(m[r] - mn);
            float lsum = 0.f;
            #pragma unroll
            for (int sub = 0; sub < 4; sub++) {
                float p = __expf(S[sub][r] - mn);
                S[sub][r] = p;
                lsum += p;
            }
            #pragma unroll
            for (int o = 8; o > 0; o >>= 1) lsum += __shfl_xor(lsum, o);
            l[r] = l[r] * sc + lsum;
            m[r] = mn;
            #pragma unroll
            for (int ds = 0; ds < 4; ds++) Oacc[ds][r] *= sc;
        }

        #pragma unroll
        for (int sub = 0; sub < 4; sub++)
            #pragma unroll
            for (int r = 0; r < 4; r++)
                Ps[w][g * 4 + r][sub * 16 + c] = f2b(S[sub][r]);

        #pragma unroll
        for (int kk = 0; kk < 2; kk++) {
            BF8 pa;
            pa.s = *(const s16x8*)&Ps[w][c][8 * g + kk * 32];
            #pragma unroll
            for (int ds = 0; ds < 4; ds++) {
                BF8 vb;
                vb.s = *(const s16x8*)&Vt[cur][ds * 16 + c][8 * g + kk * 32];
                Oacc[ds] = __builtin_amdgcn_mfma_f32_16x16x32_bf16(pa.b, vb.b, Oacc[ds], 0, 0, 0);
            }
        }

        if (i + 1 < nAct) WRITET(cur ^ 1);      // other buffer: no conflict with readers
        __syncthreads();                         // writes visible; readers of cur done
    }
#undef LOADT
#undef WRITET

    #pragma unroll
    for (int r = 0; r < 4; r++) {
        float inv = 1.0f / l[r];
        int qrow = qbase + w * 16 + g * 4 + r;
        unsigned short* op = O_ + ((size_t)(b * Sq + qrow)) * D_MODEL + h * D_KH;
        #pragma unroll
        for (int ds = 0; ds < 4; ds++)
            op[ds * 16 + c] = f2b(Oacc[ds][r] * inv);
    }
}

// ---------------- layernorm(f + h), fp32 out + optional bf16 shadow -----------------
template<int WRITEB>
__global__ void ln_residual_kernel(const float* __restrict__ f, const float* __restrict__ h,
                                   const float* __restrict__ g, const float* __restrict__ bb,
                                   float* __restrict__ out, unsigned short* __restrict__ outb) {
    int row  = blockIdx.x * 4 + threadIdx.x / 64;
    int lane = threadIdx.x % 64;
    const float* fr = f + (size_t)row * D_MODEL;
    const float* hr = h + (size_t)row * D_MODEL;
    float v[8];
    float s = 0.f;
    #pragma unroll
    for (int i = 0; i < 8; i++) {
        v[i] = fr[lane + i * 64] + hr[lane + i * 64];
        s += v[i];
    }
    #pragma unroll
    for (int o = 32; o > 0; o >>= 1) s += __shfl_xor(s, o);
    float mu = s * (1.0f / 512.0f);
    float ss = 0.f;
    #pragma unroll
    for (int i = 0; i < 8; i++) { float d = v[i] - mu; ss += d * d; }
    #pragma unroll
    for (int o = 32; o > 0; o >>= 1) ss += __shfl_xor(ss, o);
    float var = ss * (1.0f / 512.0f);
    float inv = 1.0f / sqrtf(var + 1e-6f);
    #pragma unroll
    for (int i = 0; i < 8; i++) {
        int d = lane + i * 64;
        float o2 = g[d] * (v[i] - mu) * inv + bb[d];
        out[(size_t)row * D_MODEL + d] = o2;
        if (WRITEB) outb[(size_t)row * D_MODEL + d] = f2b(o2);
    }
}

extern "C" void kernel_launch(void* const* d_in, const int* in_sizes, int n_in,
                              void* d_out, int out_size, void* d_ws, size_t ws_size,
                              hipStream_t stream) {
    const int*   dec     = (const int*)d_in[0];
    const int*   enc_ids = (const int*)d_in[1];
    const float* enc_out = (const float*)d_in[2];
    const float* emb     = (const float*)d_in[3];
    const float* self_W  = (const float*)d_in[4];
    const float* self_b  = (const float*)d_in[5];
    const float* enc_W   = (const float*)d_in[6];
    const float* enc_b   = (const float*)d_in[7];
    const float* W1      = (const float*)d_in[8];
    const float* b1      = (const float*)d_in[9];
    const float* W2      = (const float*)d_in[10];
    const float* b2      = (const float*)d_in[11];
    const float* ln_g    = (const float*)d_in[12];
    const float* ln_b    = (const float*)d_in[13];
    float* out = (float*)d_out;

    const size_t NTOK = (size_t)BSZ * SEQ;      // 4096
    float* x  = (float*)d_ws;
    float* bA = x + NTOK * D_MODEL;
    unsigned short* xb   = (unsigned short*)(bA + NTOK * D_MODEL);
    unsigned short* encb = xb + NTOK * D_MODEL;
    unsigned short* bQ = encb + NTOK * D_MODEL;
    unsigned short* bK = bQ + NTOK * D_MODEL;
    unsigned short* bV = bK + NTOK * D_MODEL;
    unsigned short* bD = bV + NTOK * D_MODEL;
    unsigned short* bH = bQ;                    // 4096*2048 bf16 aliases bQ..bD
    unsigned short* wtS  = bD + NTOK * D_MODEL;
    unsigned short* wtE  = wtS + (size_t)N_LAYERS * 4 * D_MODEL * D_MODEL;
    unsigned short* wtF1 = wtE + (size_t)N_LAYERS * 4 * D_MODEL * D_MODEL;
    unsigned short* wtF2 = wtF1 + (size_t)N_LAYERS * D_MODEL * D_FF;
    unsigned short* crossKV = wtF2 + (size_t)N_LAYERS * D_FF * D_MODEL;  // 8 x NTOK x D_MODEL (32MB)
    int* cntEnc    = (int*)(crossKV + (size_t)8 * NTOK * D_MODEL);
    int* anyPadDec = cntEnc + BSZ;
    int* listEnc   = anyPadDec + BSZ * (SEQ / 64);

    dim3 blk(256);
    {
        const int NE = (int)(NTOK * D_MODEL);
        int total = NE + NE / 4;
        embed_cvt_kernel<<<dim3((total + 255) / 256), blk, 0, stream>>>(dec, emb, x, xb, enc_out, encb);
    }
    prep_kernel<<<dim3(BSZ), dim3(64), 0, stream>>>(dec, enc_ids, cntEnc, listEnc, anyPadDec);
    wt_all_kernel<<<dim3(4096), blk, 0, stream>>>(self_W, enc_W, W1, W2, wtS, wtE, wtF1, wtF2);
    gemm_kv_kernel<<<dim3((unsigned)(NTOK / 64), D_MODEL / 64, 8), blk, 0, stream>>>(encb, wtE, enc_b, crossKV);

    int M = (int)NTOK;
    dim3 gqkv(M / 64, D_MODEL / 64, 3);  // merged self-QKV (64x64): 1536 blocks
    dim3 gp64(M / 64, D_MODEL / 64);     // 64x64: 512 blocks = 2/CU exact
    dim3 gf1 (M / 128, D_FF / 128);      // FFN1 (128x128): 512 blocks = 2/CU exact
    dim3 gf2 (M / 64, D_MODEL / 64);     // FFN2 (64x64): 512 blocks = 2/CU exact
    int nAttnBlk = BSZ * N_HEADS * (SEQ / 64);

    const size_t WT = (size_t)D_MODEL * D_MODEL;
    for (int L = 0; L < N_LAYERS; L++) {
        const unsigned short* sWt = wtS + (size_t)L * 4 * WT;
        const unsigned short* eWt = wtE + (size_t)L * 4 * WT;
        const float* sb = self_b + (size_t)L * 4 * D_MODEL;
        const float* eb = enc_b  + (size_t)L * 4 * D_MODEL;
        const float* g  = ln_g   + (size_t)L * 3 * D_MODEL;
        const float* bs = ln_b   + (size_t)L * 3 * D_MODEL;
        const unsigned short* bKc = crossKV + (size_t)(L * 2 + 0) * NTOK * D_MODEL;
        const unsigned short* bVc = crossKV + (size_t)(L * 2 + 1) * NTOK * D_MODEL;

        // ---- self attention ----
        gemm64_qkv_kernel<<<gqkv, blk, 0, stream>>>(xb, sWt, sb, bQ, bK, bV);
        attn_kernel<1><<<dim3(nAttnBlk), blk, 0, stream>>>(bQ, bK, bV, dec, listEnc, cntEnc, anyPadDec, bD, SEQ, SEQ);
        gemm64_kernel<0,0><<<gp64, blk, 0, stream>>>(bD, sWt + 3 * WT, sb + 3 * D_MODEL, bA, M, D_MODEL, D_MODEL);
        ln_residual_kernel<1><<<dim3(M / 4), blk, 0, stream>>>(bA, x, g + 0 * D_MODEL, bs + 0 * D_MODEL, x, xb);

        // ---- cross attention (K/V precomputed in prologue; Q-only projection) ----
        gemm64_kernel<1,0><<<gp64, blk, 0, stream>>>(xb, eWt + 0 * WT, eb + 0 * D_MODEL, bQ, M, D_MODEL, D_MODEL);
        attn_kernel<0><<<dim3(nAttnBlk), blk, 0, stream>>>(bQ, bKc, bVc, enc_ids, listEnc, cntEnc, anyPadDec, bD, SEQ, SEQ);
        gemm64_kernel<0,0><<<gp64, blk, 0, stream>>>(bD, eWt + 3 * WT, eb + 3 * D_MODEL, bA, M, D_MODEL, D_MODEL);
        ln_residual_kernel<1><<<dim3(M / 4), blk, 0, stream>>>(bA, x, g + 1 * D_MODEL, bs + 1 * D_MODEL, x, xb);

        // ---- FFN ----
        gemm128_kernel<1,1><<<gf1, blk, 0, stream>>>(xb, wtF1 + (size_t)L * D_MODEL * D_FF, b1 + (size_t)L * D_FF,    bH, M, D_FF,    D_MODEL);
        gemm64_kernel<0,0><<<gf2, blk, 0, stream>>>(bH, wtF2 + (size_t)L * D_FF * D_MODEL, b2 + (size_t)L * D_MODEL, bA, M, D_MODEL, D_FF);
        float* lnout = (L == N_LAYERS - 1) ? out : x;
        ln_residual_kernel<1><<<dim3(M / 4), blk, 0, stream>>>(bA, x, g + 2 * D_MODEL, bs + 2 * D_MODEL, lnout, xb);
    }
}

// Round 15
// 570.295 us; speedup vs baseline: 1.0166x; 1.0166x over previous
//
#include <hip/hip_runtime.h>
#include <math.h>

#define D_MODEL 512
#define N_HEADS 8
#define D_KH    64
#define D_FF    2048
#define N_LAYERS 4
#define BSZ     4
#define SEQ     1024

typedef __attribute__((ext_vector_type(8))) __bf16 bf16x8;
typedef __attribute__((ext_vector_type(8))) short  s16x8;
typedef __attribute__((ext_vector_type(4))) float  f32x4;

union BF8 { s16x8 s; bf16x8 b; };

static __device__ inline unsigned short f2b(float f) {
    unsigned u = __float_as_uint(f);
    unsigned r = (u + 0x7fffu + ((u >> 16) & 1u)) >> 16;   // RNE
    return (unsigned short)r;
}

// async global->LDS 16B: lds dest = wave-uniform base + lane*16; global src per-lane.
static __device__ __forceinline__ void async16(const unsigned short* g, unsigned short* l) {
    __builtin_amdgcn_global_load_lds((const __attribute__((address_space(1))) unsigned int*)g,
                                     (__attribute__((address_space(3))) unsigned int*)l, 16, 0, 0);
}

// ---------------- embedding + sinusoid positional encoding (fp32 + bf16 shadow) -----
__global__ void embed_kernel(const int* __restrict__ dec, const float* __restrict__ emb,
                             float* __restrict__ x, unsigned short* __restrict__ xb) {
    int idx = blockIdx.x * blockDim.x + threadIdx.x;
    int d  = idx % D_MODEL;
    int bs = idx / D_MODEL;
    int s  = bs % SEQ;
    int tok = dec[bs];
    float pos = (float)(s + 5);
    float e = (float)(d & ~1) * (1.0f / (float)D_MODEL);
    float ang = pos * __expf(-9.210340372f * e);        // 10000^-e
    float pe = (d & 1) ? __cosf(ang) : __sinf(ang);
    float v = emb[(size_t)tok * D_MODEL + d] + pe;
    x[idx] = v;
    xb[idx] = f2b(v);
}

// ---------------- fp32 -> bf16 bulk convert (enc_out, once) -------------------------
__global__ void cvt_bf16_kernel(const float* __restrict__ in, unsigned short* __restrict__ outp, int n4) {
    int i = blockIdx.x * blockDim.x + threadIdx.x;
    if (i < n4) {
        float4 f = ((const float4*)in)[i];
        ushort4 h;
        h.x = f2b(f.x); h.y = f2b(f.y); h.z = f2b(f.z); h.w = f2b(f.w);
        ((ushort4*)outp)[i] = h;
    }
}

// ---------------- ALL weight transposes in one launch: src[K][N] f32 -> dst[N][K] bf16
__global__ void wt_all_kernel(const float* __restrict__ selfW, const float* __restrict__ encW,
                              const float* __restrict__ W1, const float* __restrict__ W2,
                              unsigned short* __restrict__ wtS, unsigned short* __restrict__ wtE,
                              unsigned short* __restrict__ wtF1, unsigned short* __restrict__ wtF2) {
    __shared__ unsigned short Tb[64][72];
    int tile = blockIdx.x;                 // 4096 tiles, 1024 per weight group
    int which = tile >> 10, rem = tile & 1023;
    const float* src; unsigned short* dst; int K, N, z, kt, ntile;
    if (which <= 1) {
        src = which ? encW : selfW; dst = which ? wtE : wtS;
        K = 512; N = 512;
        z = rem >> 6; int r2 = rem & 63; kt = r2 & 7; ntile = r2 >> 3;
    } else if (which == 2) {
        src = W1; dst = wtF1; K = 512; N = 2048;
        z = rem >> 8; int r2 = rem & 255; kt = r2 & 7; ntile = r2 >> 3;
    } else {
        src = W2; dst = wtF2; K = 2048; N = 512;
        z = rem >> 8; int r2 = rem & 255; kt = r2 >> 3; ntile = r2 & 7;
    }
    int k0 = kt * 64, n0 = ntile * 64;
    size_t zoff = (size_t)z * K * N;
    src += zoff; dst += zoff;
    int t = threadIdx.x;
    int kr = t & 63, sg = t >> 6;
    const float* sp = src + (size_t)(k0 + kr) * N + n0 + sg * 16;
    #pragma unroll
    for (int j = 0; j < 4; j++) {
        float4 f = *(const float4*)(sp + 4 * j);
        Tb[sg * 16 + 4 * j + 0][kr] = f2b(f.x);
        Tb[sg * 16 + 4 * j + 1][kr] = f2b(f.y);
        Tb[sg * 16 + 4 * j + 2][kr] = f2b(f.z);
        Tb[sg * 16 + 4 * j + 3][kr] = f2b(f.w);
    }
    __syncthreads();
    unsigned short* dp = dst + (size_t)(n0 + kr) * K + k0 + sg * 16;
    *(s16x8*)(dp)     = *(const s16x8*)&Tb[kr][sg * 16];
    *(s16x8*)(dp + 8) = *(const s16x8*)&Tb[kr][sg * 16 + 8];
}

// ---------------- mask prep: enc pad-key compaction + dec pad-tile flags ------------
__global__ void prep_kernel(const int* __restrict__ dec, const int* __restrict__ enc,
                            int* __restrict__ cntEnc, int* __restrict__ listEnc,
                            int* __restrict__ anyPadDec) {
    int b = blockIdx.x;
    int lane = threadIdx.x;
    int base = 0;
    for (int c0 = 0; c0 < SEQ; c0 += 64) {
        bool z = (enc[b * SEQ + c0 + lane] == 0);
        unsigned long long mask = __ballot(z);
        int pre = __popcll(mask & ((1ull << lane) - 1ull));
        if (z) listEnc[b * SEQ + base + pre] = c0 + lane;
        base += __popcll(mask);
    }
    if (lane == 0) cntEnc[b] = base;
    for (int c0 = 0; c0 < SEQ; c0 += 64) {
        bool z = (dec[b * SEQ + c0 + lane] == 0);
        unsigned long long mask = __ballot(z);
        if (lane == 0) anyPadDec[b * (SEQ / 64) + (c0 >> 6)] = (mask != 0ull) ? 1 : 0;
    }
}

// ---------------- bf16 MFMA GEMM 128x64, global_load_lds + XOR swizzle, dbuf --------
// QKV=1: blockIdx.y spans 3 concat weight matrices; j=y>>3, A1 for j>=1, C1/C2 j=1/2.
template<int OUTBF16, int RELU, int QKV>
__launch_bounds__(256, 3)
__global__ void gemm_lds_kernel(const unsigned short* __restrict__ A, const unsigned short* __restrict__ A1,
                                const unsigned short* __restrict__ Wt, const float* __restrict__ bias,
                                void* __restrict__ C_, void* __restrict__ C1, void* __restrict__ C2,
                                int M, int N, int K) {
    __shared__ unsigned short lds[2][12288];   // [A 128x64 | B 64x64] x 2 buf = 48KB
    int m0 = blockIdx.x * 128, n0;
    if (QKV) {
        int j = blockIdx.y >> 3;
        n0 = (int)(blockIdx.y & 7) * 64;
        Wt += (size_t)j * (D_MODEL * D_MODEL);
        bias += j * D_MODEL;
        if (j) A = A1;
        if (j == 1) C_ = C1; else if (j == 2) C_ = C2;
    } else n0 = blockIdx.y * 64;

    int t = threadIdx.x, w = t >> 6, lane = t & 63;
    int g = lane >> 4, c = lane & 15;
    int l3 = lane >> 3, l7 = lane & 7;
    int srcoff = 8 * (l7 ^ l3);                 // inverse-swizzled elem col within k-tile

    const unsigned short* Abase = A  + (size_t)m0 * K;
    const unsigned short* Bbase = Wt + (size_t)n0 * K;

    f32x4 acc[2][4];
    #pragma unroll
    for (int mi = 0; mi < 2; mi++)
        #pragma unroll
        for (int nj = 0; nj < 4; nj++) acc[mi][nj] = (f32x4){0.f, 0.f, 0.f, 0.f};

#define STAGE(BUF, KT) do {                                                         \
        unsigned short* Lb_ = &lds[BUF][0];                                         \
        int k0_ = (KT) * 64;                                                        \
        _Pragma("unroll")                                                           \
        for (int i_ = 0; i_ < 4; i_++) {                                            \
            int q_ = w * 4 + i_;                                                    \
            async16(Abase + (size_t)(q_ * 8 + l3) * K + k0_ + srcoff, Lb_ + q_ * 512); \
        }                                                                           \
        _Pragma("unroll")                                                           \
        for (int i_ = 0; i_ < 2; i_++) {                                            \
            int q_ = w * 2 + i_;                                                    \
            async16(Bbase + (size_t)(q_ * 8 + l3) * K + k0_ + srcoff, Lb_ + 8192 + q_ * 512); \
        }                                                                           \
    } while (0)

    int nt = K >> 6;
    STAGE(0, 0);
    __syncthreads();
    for (int kt = 0; kt < nt; kt++) {
        int cur = kt & 1;
        if (kt + 1 < nt) STAGE(cur ^ 1, kt + 1);
        const unsigned short* Lb = &lds[cur][0];
        BF8 a[2][2], b[2][4];
        #pragma unroll
        for (int kk = 0; kk < 2; kk++) {
            int xo = (kk * 32 + g * 8) ^ ((c & 7) * 8);
            #pragma unroll
            for (int mi = 0; mi < 2; mi++)
                a[kk][mi].s = *(const s16x8*)&Lb[(w * 32 + mi * 16 + c) * 64 + xo];
            #pragma unroll
            for (int nj = 0; nj < 4; nj++)
                b[kk][nj].s = *(const s16x8*)&Lb[8192 + (nj * 16 + c) * 64 + xo];
        }
        #pragma unroll
        for (int kk = 0; kk < 2; kk++)
            #pragma unroll
            for (int mi = 0; mi < 2; mi++)
                #pragma unroll
                for (int nj = 0; nj < 4; nj++)
                    acc[mi][nj] = __builtin_amdgcn_mfma_f32_16x16x32_bf16(a[kk][mi].b, b[kk][nj].b, acc[mi][nj], 0, 0, 0);
        __syncthreads();
    }
#undef STAGE

    #pragma unroll
    for (int mi = 0; mi < 2; mi++) {
        #pragma unroll
        for (int nj = 0; nj < 4; nj++) {
            #pragma unroll
            for (int r = 0; r < 4; r++) {
                int row = m0 + w * 32 + mi * 16 + g * 4 + r;
                int col = n0 + nj * 16 + c;
                float v = acc[mi][nj][r] + bias[col];
                if (RELU) v = fmaxf(v, 0.0f);
                if (OUTBF16) ((unsigned short*)C_)[(size_t)row * N + col] = f2b(v);
                else         ((float*)C_)[(size_t)row * N + col] = v;
            }
        }
    }
}

// ---------------- bf16 MFMA GEMM 64x64 (latency-optimized: 512 blocks = 2/CU) -------
template<int OUTBF16, int RELU>
__launch_bounds__(256, 4)
__global__ void gemm64_kernel(const unsigned short* __restrict__ A,
                              const unsigned short* __restrict__ Wt, const float* __restrict__ bias,
                              void* __restrict__ C_, int M, int N, int K) {
    __shared__ unsigned short lds[2][8192];    // [A 64x64 | B 64x64] x 2 buf = 32KB
    int m0 = blockIdx.x * 64, n0 = blockIdx.y * 64;

    int t = threadIdx.x, w = t >> 6, lane = t & 63;
    int wm = w >> 1, wn = w & 1;               // 2x2 wave grid, wave tile 32x32
    int g = lane >> 4, c = lane & 15;
    int l3 = lane >> 3, l7 = lane & 7;
    int srcoff = 8 * (l7 ^ l3);

    const unsigned short* Abase = A  + (size_t)m0 * K;
    const unsigned short* Bbase = Wt + (size_t)n0 * K;

    f32x4 acc[2][2];
    #pragma unroll
    for (int mi = 0; mi < 2; mi++)
        #pragma unroll
        for (int nj = 0; nj < 2; nj++) acc[mi][nj] = (f32x4){0.f, 0.f, 0.f, 0.f};

#define STAGE64(BUF, KT) do {                                                       \
        unsigned short* Lb_ = &lds[BUF][0];                                         \
        int k0_ = (KT) * 64;                                                        \
        _Pragma("unroll")                                                           \
        for (int i_ = 0; i_ < 2; i_++) {                                            \
            int q_ = w * 2 + i_;                                                    \
            async16(Abase + (size_t)(q_ * 8 + l3) * K + k0_ + srcoff, Lb_ + q_ * 512); \
            async16(Bbase + (size_t)(q_ * 8 + l3) * K + k0_ + srcoff, Lb_ + 4096 + q_ * 512); \
        }                                                                           \
    } while (0)

    int nt = K >> 6;
    STAGE64(0, 0);
    __syncthreads();
    for (int kt = 0; kt < nt; kt++) {
        int cur = kt & 1;
        if (kt + 1 < nt) STAGE64(cur ^ 1, kt + 1);
        const unsigned short* Lb = &lds[cur][0];
        BF8 a[2][2], b[2][2];
        #pragma unroll
        for (int kk = 0; kk < 2; kk++) {
            int xo = (kk * 32 + g * 8) ^ ((c & 7) * 8);
            #pragma unroll
            for (int mi = 0; mi < 2; mi++)
                a[kk][mi].s = *(const s16x8*)&Lb[(wm * 32 + mi * 16 + c) * 64 + xo];
            #pragma unroll
            for (int nj = 0; nj < 2; nj++)
                b[kk][nj].s = *(const s16x8*)&Lb[4096 + (wn * 32 + nj * 16 + c) * 64 + xo];
        }
        #pragma unroll
        for (int kk = 0; kk < 2; kk++)
            #pragma unroll
            for (int mi = 0; mi < 2; mi++)
                #pragma unroll
                for (int nj = 0; nj < 2; nj++)
                    acc[mi][nj] = __builtin_amdgcn_mfma_f32_16x16x32_bf16(a[kk][mi].b, b[kk][nj].b, acc[mi][nj], 0, 0, 0);
        __syncthreads();
    }
#undef STAGE64

    #pragma unroll
    for (int mi = 0; mi < 2; mi++) {
        #pragma unroll
        for (int nj = 0; nj < 2; nj++) {
            #pragma unroll
            for (int r = 0; r < 4; r++) {
                int row = m0 + wm * 32 + mi * 16 + g * 4 + r;
                int col = n0 + wn * 32 + nj * 16 + c;
                float v = acc[mi][nj][r] + bias[col];
                if (RELU) v = fmaxf(v, 0.0f);
                if (OUTBF16) ((unsigned short*)C_)[(size_t)row * N + col] = f2b(v);
                else         ((float*)C_)[(size_t)row * N + col] = v;
            }
        }
    }
}

// ---------------- bf16 MFMA GEMM 128x128, wave tile 64x64 (FFN1: 512 blocks=2/CU) ---
template<int OUTBF16, int RELU>
__launch_bounds__(256, 2)
__global__ void gemm128_kernel(const unsigned short* __restrict__ A,
                               const unsigned short* __restrict__ Wt, const float* __restrict__ bias,
                               void* __restrict__ C_, int M, int N, int K) {
    __shared__ unsigned short lds[2][16384];   // [A 128x64 | B 128x64] x 2 buf = 64KB
    int m0 = blockIdx.x * 128, n0 = blockIdx.y * 128;

    int t = threadIdx.x, w = t >> 6, lane = t & 63;
    int wm = w >> 1, wn = w & 1;               // 2x2 wave grid, wave tile 64x64
    int g = lane >> 4, c = lane & 15;
    int l3 = lane >> 3, l7 = lane & 7;
    int srcoff = 8 * (l7 ^ l3);

    const unsigned short* Abase = A  + (size_t)m0 * K;
    const unsigned short* Bbase = Wt + (size_t)n0 * K;

    f32x4 acc[4][4];
    #pragma unroll
    for (int mi = 0; mi < 4; mi++)
        #pragma unroll
        for (int nj = 0; nj < 4; nj++) acc[mi][nj] = (f32x4){0.f, 0.f, 0.f, 0.f};

#define STAGE128(BUF, KT) do {                                                      \
        unsigned short* Lb_ = &lds[BUF][0];                                         \
        int k0_ = (KT) * 64;                                                        \
        _Pragma("unroll")                                                           \
        for (int i_ = 0; i_ < 4; i_++) {                                            \
            int q_ = w * 4 + i_;                                                    \
            async16(Abase + (size_t)(q_ * 8 + l3) * K + k0_ + srcoff, Lb_ + q_ * 512); \
            async16(Bbase + (size_t)(q_ * 8 + l3) * K + k0_ + srcoff, Lb_ + 8192 + q_ * 512); \
        }                                                                           \
    } while (0)

    int nt = K >> 6;
    STAGE128(0, 0);
    __syncthreads();
    for (int kt = 0; kt < nt; kt++) {
        int cur = kt & 1;
        if (kt + 1 < nt) STAGE128(cur ^ 1, kt + 1);
        const unsigned short* Lb = &lds[cur][0];
        BF8 a[2][4], b[2][4];
        #pragma unroll
        for (int kk = 0; kk < 2; kk++) {
            int xo = (kk * 32 + g * 8) ^ ((c & 7) * 8);
            #pragma unroll
            for (int mi = 0; mi < 4; mi++)
                a[kk][mi].s = *(const s16x8*)&Lb[(wm * 64 + mi * 16 + c) * 64 + xo];
            #pragma unroll
            for (int nj = 0; nj < 4; nj++)
                b[kk][nj].s = *(const s16x8*)&Lb[8192 + (wn * 64 + nj * 16 + c) * 64 + xo];
        }
        #pragma unroll
        for (int kk = 0; kk < 2; kk++)
            #pragma unroll
            for (int mi = 0; mi < 4; mi++)
                #pragma unroll
                for (int nj = 0; nj < 4; nj++)
                    acc[mi][nj] = __builtin_amdgcn_mfma_f32_16x16x32_bf16(a[kk][mi].b, b[kk][nj].b, acc[mi][nj], 0, 0, 0);
        __syncthreads();
    }
#undef STAGE128

    #pragma unroll
    for (int mi = 0; mi < 4; mi++) {
        #pragma unroll
        for (int nj = 0; nj < 4; nj++) {
            #pragma unroll
            for (int r = 0; r < 4; r++) {
                int row = m0 + wm * 64 + mi * 16 + g * 4 + r;
                int col = n0 + wn * 64 + nj * 16 + c;
                float v = acc[mi][nj][r] + bias[col];
                if (RELU) v = fmaxf(v, 0.0f);
                if (OUTBF16) ((unsigned short*)C_)[(size_t)row * N + col] = f2b(v);
                else         ((float*)C_)[(size_t)row * N + col] = v;
            }
        }
    }
}

// ---------------- MFMA bf16 flash attention: 4 waves, K/V LDS double-buffered -------
#define RS 72
template<int MODE>
__global__ void attn_kernel(const unsigned short* __restrict__ Q, const unsigned short* __restrict__ K,
                            const unsigned short* __restrict__ V, const int* __restrict__ ids,
                            const int* __restrict__ list, const int* __restrict__ cnt,
                            const int* __restrict__ anyPad,
                            unsigned short* __restrict__ O_, int Sq, int Sk) {
    __shared__ unsigned short Kl[2][64][RS];
    __shared__ unsigned short Vt[2][64][RS];
    __shared__ unsigned short Ps[4][16][RS];
    __shared__ short act[16];
    __shared__ int nActS;

    int blk = blockIdx.x;
    int qt, bh;
    if (MODE) {
        int hi = blk >> 8, pair = blk & 255;
        bh = pair >> 3;
        int qtp = pair & 7;
        qt = hi ? (15 - qtp) : qtp;             // pair work: (qtp+1)+(16-qtp)=17 tiles
    } else {
        qt = blk & 15;
        bh = blk >> 4;
    }
    int h = bh % N_HEADS;
    int b = bh / N_HEADS;
    int qbase = qt * 64;
    int t = threadIdx.x;
    int w = t >> 6, lane = t & 63;
    int g = lane >> 4, c = lane & 15;

    BF8 qf[2];
    {
        int qrow = qbase + w * 16 + c;
        const unsigned short* qp = Q + ((size_t)(b * Sq + qrow)) * D_MODEL + h * D_KH;
        qf[0].s = *(const s16x8*)(qp + 8 * g);
        qf[1].s = *(const s16x8*)(qp + 8 * g + 32);
    }

    int nk = 0;
    bool gathered = false;
    if (!MODE) {
        nk = cnt[b];
        gathered = (nk > 0);
    }

    if (t == 0) {
        int n = 0;
        if (MODE) {
            for (int kt2 = 0; kt2 < (Sk >> 6); kt2++)
                if (kt2 <= qt || anyPad[b * (Sk >> 6) + kt2]) act[n++] = (short)kt2;
        } else {
            int tt = gathered ? ((nk + 63) >> 6) : (Sk >> 6);
            for (int kt2 = 0; kt2 < tt; kt2++) act[n++] = (short)kt2;
        }
        nActS = n;
    }
    __syncthreads();
    int nAct = nActS;

    float m[4], l[4];
    f32x4 Oacc[4];
    #pragma unroll
    for (int r = 0; r < 4; r++) { m[r] = -INFINITY; l[r] = 0.0f; }
    #pragma unroll
    for (int ds = 0; ds < 4; ds++) Oacc[ds] = (f32x4){0.f, 0.f, 0.f, 0.f};

    s16x8 kreg0, kreg1, vreg0, vreg1;
    int kr0 = t >> 3,        ks0 = t & 7;
    int kr1 = (t + 256) >> 3, ks1 = (t + 256) & 7;

#define LOADT(KT) do {                                                                \
        int k0_ = (KT) * 64;                                                          \
        int krow0 = k0_ + kr0, krow1 = k0_ + kr1;                                     \
        if (gathered) {                                                               \
            krow0 = list[b * Sk + (krow0 < nk ? krow0 : nk - 1)];                     \
            krow1 = list[b * Sk + (krow1 < nk ? krow1 : nk - 1)];                     \
        }                                                                             \
        kreg0 = *(const s16x8*)(K + ((size_t)(b * Sk + krow0)) * D_MODEL + h * D_KH + ks0 * 8); \
        kreg1 = *(const s16x8*)(K + ((size_t)(b * Sk + krow1)) * D_MODEL + h * D_KH + ks1 * 8); \
        int li = k0_ + lane, vrow = li;                                               \
        if (gathered) vrow = list[b * Sk + (li < nk ? li : nk - 1)];                  \
        const unsigned short* vp = V + ((size_t)(b * Sk + vrow)) * D_MODEL + h * D_KH + w * 16; \
        vreg0 = *(const s16x8*)(vp);                                                  \
        vreg1 = *(const s16x8*)(vp + 8);                                              \
    } while (0)

#define WRITET(BUF) do {                                                              \
        *(s16x8*)&Kl[BUF][kr0][ks0 * 8] = kreg0;                                      \
        *(s16x8*)&Kl[BUF][kr1][ks1 * 8] = kreg1;                                      \
        _Pragma("unroll")                                                             \
        for (int j = 0; j < 8; j++) Vt[BUF][w * 16 + j][lane] = ((unsigned short*)&vreg0)[j]; \
        _Pragma("unroll")                                                             \
        for (int j = 0; j < 8; j++) Vt[BUF][w * 16 + 8 + j][lane] = ((unsigned short*)&vreg1)[j]; \
    } while (0)

    LOADT(act[0]);
    WRITET(0);
    __syncthreads();
    for (int i = 0; i < nAct; i++) {
        int cur = i & 1;
        int k0 = (int)act[i] * 64;
        if (i + 1 < nAct) LOADT(act[i + 1]);    // latency hides under compute below

        f32x4 S[4];
        #pragma unroll
        for (int sub = 0; sub < 4; sub++) {
            BF8 b0, b1;
            b0.s = *(const s16x8*)&Kl[cur][sub * 16 + c][8 * g];
            b1.s = *(const s16x8*)&Kl[cur][sub * 16 + c][8 * g + 32];
            f32x4 s = (f32x4){0.f, 0.f, 0.f, 0.f};
            s = __builtin_amdgcn_mfma_f32_16x16x32_bf16(qf[0].b, b0.b, s, 0, 0, 0);
            s = __builtin_amdgcn_mfma_f32_16x16x32_bf16(qf[1].b, b1.b, s, 0, 0, 0);
            S[sub] = s;
        }

        #pragma unroll
        for (int sub = 0; sub < 4; sub++) {
            int k = k0 + sub * 16 + c;
            bool pad;
            if (MODE) pad = (ids[b * Sk + k] == 0);
            else      pad = gathered ? (k < nk) : false;
            #pragma unroll
            for (int r = 0; r < 4; r++) {
                bool att;
                if (MODE) {
                    int qrow = qbase + w * 16 + g * 4 + r;
                    att = pad || (k <= qrow);
                } else att = pad;
                S[sub][r] = att ? S[sub][r] * 0.125f : -1e9f;
            }
        }

        #pragma unroll
        for (int r = 0; r < 4; r++) {
            float mx = fmaxf(fmaxf(S[0][r], S[1][r]), fmaxf(S[2][r], S[3][r]));
            #pragma unroll
            for (int o = 8; o > 0; o >>= 1) mx = fmaxf(mx, __shfl_xor(mx, o));
            float mn = fmaxf(m[r], mx);
            float sc = __expf(m[r] - mn);
            float lsum = 0.f;
            #pragma unroll
            for (int sub = 0; sub < 4; sub++) {
                float p = __expf(S[sub][r] - mn);
                S[sub][r] = p;
                lsum += p;
            }
            #pragma unroll
            for (int o = 8; o > 0; o >>= 1) lsum += __shfl_xor(lsum, o);
            l[r] = l[r] * sc + lsum;
            m[r] = mn;
            #pragma unroll
            for (int ds = 0; ds < 4; ds++) Oacc[ds][r] *= sc;
        }

        #pragma unroll
        for (int sub = 0; sub < 4; sub++)
            #pragma unroll
            for (int r = 0; r < 4; r++)
                Ps[w][g * 4 + r][sub * 16 + c] = f2b(S[sub][r]);

        #pragma unroll
        for (int kk = 0; kk < 2; kk++) {
            BF8 pa;
            pa.s = *(const s16x8*)&Ps[w][c][8 * g + kk * 32];
            #pragma unroll
            for (int ds = 0; ds < 4; ds++) {
                BF8 vb;
                vb.s = *(const s16x8*)&Vt[cur][ds * 16 + c][8 * g + kk * 32];
                Oacc[ds] = __builtin_amdgcn_mfma_f32_16x16x32_bf16(pa.b, vb.b, Oacc[ds], 0, 0, 0);
            }
        }

        if (i + 1 < nAct) WRITET(cur ^ 1);      // other buffer: no conflict with readers
        __syncthreads();                         // writes visible; readers of cur done
    }
#undef LOADT
#undef WRITET

    #pragma unroll
    for (int r = 0; r < 4; r++) {
        float inv = 1.0f / l[r];
        int qrow = qbase + w * 16 + g * 4 + r;
        unsigned short* op = O_ + ((size_t)(b * Sq + qrow)) * D_MODEL + h * D_KH;
        #pragma unroll
        for (int ds = 0; ds < 4; ds++)
            op[ds * 16 + c] = f2b(Oacc[ds][r] * inv);
    }
}

// ---------------- layernorm(f + h), fp32 out + optional bf16 shadow -----------------
template<int WRITEB>
__global__ void ln_residual_kernel(const float* __restrict__ f, const float* __restrict__ h,
                                   const float* __restrict__ g, const float* __restrict__ bb,
                                   float* __restrict__ out, unsigned short* __restrict__ outb) {
    int row  = blockIdx.x * 4 + threadIdx.x / 64;
    int lane = threadIdx.x % 64;
    const float* fr = f + (size_t)row * D_MODEL;
    const float* hr = h + (size_t)row * D_MODEL;
    float v[8];
    float s = 0.f;
    #pragma unroll
    for (int i = 0; i < 8; i++) {
        v[i] = fr[lane + i * 64] + hr[lane + i * 64];
        s += v[i];
    }
    #pragma unroll
    for (int o = 32; o > 0; o >>= 1) s += __shfl_xor(s, o);
    float mu = s * (1.0f / 512.0f);
    float ss = 0.f;
    #pragma unroll
    for (int i = 0; i < 8; i++) { float d = v[i] - mu; ss += d * d; }
    #pragma unroll
    for (int o = 32; o > 0; o >>= 1) ss += __shfl_xor(ss, o);
    float var = ss * (1.0f / 512.0f);
    float inv = 1.0f / sqrtf(var + 1e-6f);
    #pragma unroll
    for (int i = 0; i < 8; i++) {
        int d = lane + i * 64;
        float o2 = g[d] * (v[i] - mu) * inv + bb[d];
        out[(size_t)row * D_MODEL + d] = o2;
        if (WRITEB) outb[(size_t)row * D_MODEL + d] = f2b(o2);
    }
}

extern "C" void kernel_launch(void* const* d_in, const int* in_sizes, int n_in,
                              void* d_out, int out_size, void* d_ws, size_t ws_size,
                              hipStream_t stream) {
    const int*   dec     = (const int*)d_in[0];
    const int*   enc_ids = (const int*)d_in[1];
    const float* enc_out = (const float*)d_in[2];
    const float* emb     = (const float*)d_in[3];
    const float* self_W  = (const float*)d_in[4];
    const float* self_b  = (const float*)d_in[5];
    const float* enc_W   = (const float*)d_in[6];
    const float* enc_b   = (const float*)d_in[7];
    const float* W1      = (const float*)d_in[8];
    const float* b1      = (const float*)d_in[9];
    const float* W2      = (const float*)d_in[10];
    const float* b2      = (const float*)d_in[11];
    const float* ln_g    = (const float*)d_in[12];
    const float* ln_b    = (const float*)d_in[13];
    float* out = (float*)d_out;

    const size_t NTOK = (size_t)BSZ * SEQ;      // 4096
    float* x  = (float*)d_ws;
    float* bA = x + NTOK * D_MODEL;
    unsigned short* xb   = (unsigned short*)(bA + NTOK * D_MODEL);
    unsigned short* encb = xb + NTOK * D_MODEL;
    unsigned short* bQ = encb + NTOK * D_MODEL;
    unsigned short* bK = bQ + NTOK * D_MODEL;
    unsigned short* bV = bK + NTOK * D_MODEL;
    unsigned short* bD = bV + NTOK * D_MODEL;
    unsigned short* bH = bQ;                    // 4096*2048 bf16 aliases bQ..bD
    unsigned short* wtS  = bD + NTOK * D_MODEL;
    unsigned short* wtE  = wtS + (size_t)N_LAYERS * 4 * D_MODEL * D_MODEL;
    unsigned short* wtF1 = wtE + (size_t)N_LAYERS * 4 * D_MODEL * D_MODEL;
    unsigned short* wtF2 = wtF1 + (size_t)N_LAYERS * D_MODEL * D_FF;
    int* cntEnc    = (int*)(wtF2 + (size_t)N_LAYERS * D_FF * D_MODEL);
    int* anyPadDec = cntEnc + BSZ;
    int* listEnc   = anyPadDec + BSZ * (SEQ / 64);

    dim3 blk(256);
    embed_kernel<<<dim3((unsigned)(NTOK * D_MODEL / 256)), blk, 0, stream>>>(dec, emb, x, xb);
    cvt_bf16_kernel<<<dim3((unsigned)(NTOK * D_MODEL / 4 / 256)), blk, 0, stream>>>(enc_out, encb, (int)(NTOK * D_MODEL / 4));
    prep_kernel<<<dim3(BSZ), dim3(64), 0, stream>>>(dec, enc_ids, cntEnc, listEnc, anyPadDec);
    wt_all_kernel<<<dim3(4096), blk, 0, stream>>>(self_W, enc_W, W1, W2, wtS, wtE, wtF1, wtF2);

    int M = (int)NTOK;
    dim3 gqkv(M / 128, 24);            // merged QKV (128x64): 768 blocks = 3/CU exact
    dim3 gp64(M / 64, D_MODEL / 64);   // 64x64: 512 blocks = 2/CU exact
    dim3 gf1 (M / 128, D_FF / 128);    // FFN1 (128x128): 512 blocks = 2/CU exact
    dim3 gf2 (M / 64, D_MODEL / 64);   // FFN2 (64x64): 512 blocks = 2/CU exact
    int nAttnBlk = BSZ * N_HEADS * (SEQ / 64);

    const size_t WT = (size_t)D_MODEL * D_MODEL;
    for (int L = 0; L < N_LAYERS; L++) {
        const unsigned short* sWt = wtS + (size_t)L * 4 * WT;
        const unsigned short* eWt = wtE + (size_t)L * 4 * WT;
        const float* sb = self_b + (size_t)L * 4 * D_MODEL;
        const float* eb = enc_b  + (size_t)L * 4 * D_MODEL;
        const float* g  = ln_g   + (size_t)L * 3 * D_MODEL;
        const float* bs = ln_b   + (size_t)L * 3 * D_MODEL;

        // ---- self attention ----
        gemm_lds_kernel<1,0,1><<<gqkv, blk, 0, stream>>>(xb, xb, sWt, sb, bQ, bK, bV, M, D_MODEL, D_MODEL);
        attn_kernel<1><<<dim3(nAttnBlk), blk, 0, stream>>>(bQ, bK, bV, dec, listEnc, cntEnc, anyPadDec, bD, SEQ, SEQ);
        gemm64_kernel<0,0><<<gp64, blk, 0, stream>>>(bD, sWt + 3 * WT, sb + 3 * D_MODEL, bA, M, D_MODEL, D_MODEL);
        ln_residual_kernel<1><<<dim3(M / 4), blk, 0, stream>>>(bA, x, g + 0 * D_MODEL, bs + 0 * D_MODEL, x, xb);

        // ---- cross attention ----
        gemm_lds_kernel<1,0,1><<<gqkv, blk, 0, stream>>>(xb, encb, eWt, eb, bQ, bK, bV, M, D_MODEL, D_MODEL);
        attn_kernel<0><<<dim3(nAttnBlk), blk, 0, stream>>>(bQ, bK, bV, enc_ids, listEnc, cntEnc, anyPadDec, bD, SEQ, SEQ);
        gemm64_kernel<0,0><<<gp64, blk, 0, stream>>>(bD, eWt + 3 * WT, eb + 3 * D_MODEL, bA, M, D_MODEL, D_MODEL);
        ln_residual_kernel<1><<<dim3(M / 4), blk, 0, stream>>>(bA, x, g + 1 * D_MODEL, bs + 1 * D_MODEL, x, xb);

        // ---- FFN ----
        gemm128_kernel<1,1><<<gf1, blk, 0, stream>>>(xb, wtF1 + (size_t)L * D_MODEL * D_FF, b1 + (size_t)L * D_FF,    bH, M, D_FF,    D_MODEL);
        gemm64_kernel<0,0><<<gf2, blk, 0, stream>>>(bH, wtF2 + (size_t)L * D_FF * D_MODEL, b2 + (size_t)L * D_MODEL, bA, M, D_MODEL, D_FF);
        float* lnout = (L == N_LAYERS - 1) ? out : x;
        ln_residual_kernel<1><<<dim3(M / 4), blk, 0, stream>>>(bA, x, g + 2 * D_MODEL, bs + 2 * D_MODEL, lnout, xb);
    }
}